// Round 1
// baseline (70.908 us; speedup 1.0000x reference)
//
#include <hip/hip_runtime.h>
#include <math.h>

// One thread = one 2x2 patch = one independent 4-qubit (16-amplitude) state
// simulated entirely in registers.
// Qubit->bit mapping of the flattened state index i = a*8 + b*4 + c*2 + d:
//   qubit0 -> mask 8, qubit1 -> mask 4, qubit2 -> mask 2, qubit3 -> mask 1.
__global__ __launch_bounds__(256) void qfe_kernel(
    const float* __restrict__ x, const float* __restrict__ tp,
    float* __restrict__ out, int N)
{
    int n = blockIdx.x * blockDim.x + threadIdx.x;
    if (n >= N) return;

    // n = (b, pi, pj) with pj fastest; H=W=128, nh=nw=64.
    int b   = n >> 12;        // / 4096
    int rem = n & 4095;
    int pi  = rem >> 6;
    int pj  = rem & 63;

    const float* base = x + ((size_t)b << 14) + (pi << 8) + (pj << 1);
    float2 r0 = *reinterpret_cast<const float2*>(base);        // row 2*pi
    float2 r1 = *reinterpret_cast<const float2*>(base + 128);  // row 2*pi+1

    // Initial product state: qubit w = (cos(a_w/2), sin(a_w/2)), all real.
    float A[4][2];
    {
        float ang[4] = {r0.x, r0.y, r1.x, r1.y};
        #pragma unroll
        for (int w = 0; w < 4; ++w) {
            float s, c;
            sincosf(0.5f * ang[w], &s, &c);
            A[w][0] = c; A[w][1] = s;
        }
    }

    float re[16], im[16];
    #pragma unroll
    for (int i = 0; i < 16; ++i) {
        re[i] = A[0][(i >> 3) & 1] * A[1][(i >> 2) & 1]
              * A[2][(i >> 1) & 1] * A[3][i & 1];
        im[i] = 0.0f;
    }

    // Gate angle constants (broadcast read; L2-cached).
    float gc[6], gs[6];
    #pragma unroll
    for (int k = 0; k < 6; ++k) {
        float s, c;
        sincosf(0.5f * tp[k], &s, &c);
        gc[k] = c; gs[k] = s;
    }

    // RX(t) = [[c, -i s], [-i s, c]]
    auto apply_rx = [&](int m, float c, float s) {
        #pragma unroll
        for (int i = 0; i < 16; ++i) {
            if (i & m) continue;
            int j = i | m;
            float r0_ = re[i], i0_ = im[i], r1_ = re[j], i1_ = im[j];
            re[i] =  c * r0_ + s * i1_;
            im[i] =  c * i0_ - s * r1_;
            re[j] =  s * i0_ + c * r1_;
            im[j] = -s * r0_ + c * i1_;
        }
    };
    // RY(t) = [[c, -s], [s, c]] (real)
    auto apply_ry = [&](int m, float c, float s) {
        #pragma unroll
        for (int i = 0; i < 16; ++i) {
            if (i & m) continue;
            int j = i | m;
            float r0_ = re[i], i0_ = im[i], r1_ = re[j], i1_ = im[j];
            re[i] = c * r0_ - s * r1_;
            im[i] = c * i0_ - s * i1_;
            re[j] = s * r0_ + c * r1_;
            im[j] = s * i0_ + c * i1_;
        }
    };
    // RZ(t) = diag(e^{-it/2}, e^{+it/2})
    auto apply_rz = [&](int m, float c, float s) {
        #pragma unroll
        for (int i = 0; i < 16; ++i) {
            float r_ = re[i], i_ = im[i];
            if (i & m) { re[i] = c * r_ - s * i_; im[i] = c * i_ + s * r_; }
            else       { re[i] = c * r_ + s * i_; im[i] = c * i_ - s * r_; }
        }
    };
    // CNOT(control cm, target tm): swap target pair where control bit = 1.
    auto apply_cnot = [&](int cm, int tm) {
        #pragma unroll
        for (int i = 0; i < 16; ++i) {
            if ((i & cm) && !(i & tm)) {
                int j = i | tm;
                float tr = re[i]; re[i] = re[j]; re[j] = tr;
                float ti = im[i]; im[i] = im[j]; im[j] = ti;
            }
        }
    };

    apply_rx(8, gc[0], gs[0]);   // RX(t0) on q0
    apply_ry(4, gc[1], gs[1]);   // RY(t1) on q1
    apply_rz(2, gc[2], gs[2]);   // RZ(t2) on q2
    apply_cnot(8, 2);            // CNOT(0 -> 2)
    apply_rx(1, gc[3], gs[3]);   // RX(t3) on q3
    apply_ry(8, gc[4], gs[4]);   // RY(t4) on q0
    apply_cnot(4, 1);            // CNOT(1 -> 3)
    apply_rz(2, gc[5], gs[5]);   // RZ(t5) on q2

    // <Z_w> = sum p[i] * (bit_w(i) ? -1 : +1)
    float m0 = 0.f, m1 = 0.f, m2 = 0.f, m3 = 0.f;
    #pragma unroll
    for (int i = 0; i < 16; ++i) {
        float p = re[i] * re[i] + im[i] * im[i];
        m0 += (i & 8) ? -p : p;
        m1 += (i & 4) ? -p : p;
        m2 += (i & 2) ? -p : p;
        m3 += (i & 1) ? -p : p;
    }

    *reinterpret_cast<float4*>(out + ((size_t)n << 2)) = make_float4(m0, m1, m2, m3);
}

extern "C" void kernel_launch(void* const* d_in, const int* in_sizes, int n_in,
                              void* d_out, int out_size, void* d_ws, size_t ws_size,
                              hipStream_t stream) {
    const float* x  = (const float*)d_in[0];
    const float* tp = (const float*)d_in[1];
    float* out = (float*)d_out;

    int N = in_sizes[0] / 4;  // number of 2x2 patches = 524288
    const int threads = 256;
    int blocks = (N + threads - 1) / threads;
    qfe_kernel<<<blocks, threads, 0, stream>>>(x, tp, out, N);
}

// Round 2
// 67.164 us; speedup vs baseline: 1.0557x; 1.0557x over previous
//
#include <hip/hip_runtime.h>
#include <math.h>

// One thread = one 2x2 patch = one independent 4-qubit (16-amplitude) state
// simulated entirely in registers. CNOTs are compile-time register
// permutations (loops fully unrolled) — zero instructions.
// Qubit->bit mapping of state index i: q0->8, q1->4, q2->2, q3->1.
//
// All trig via __sincosf (native v_sin_f32/v_cos_f32): inputs are N(0,1)
// pixels and [0,2pi) params, well within native-accuracy range; threshold
// is 2e-2 absolute, native error ~1e-5.
__global__ __launch_bounds__(256) void qfe_kernel(
    const float* __restrict__ x, const float* __restrict__ tp,
    float* __restrict__ out, int N)
{
    int n = blockIdx.x * blockDim.x + threadIdx.x;
    if (n >= N) return;

    // n = (b, pi, pj), pj fastest; H=W=128, nh=nw=64.
    int b   = n >> 12;
    int rem = n & 4095;
    int pi  = rem >> 6;
    int pj  = rem & 63;

    const float* base = x + ((size_t)b << 14) + (pi << 8) + (pj << 1);
    float2 r0 = *reinterpret_cast<const float2*>(base);        // row 2*pi
    float2 r1 = *reinterpret_cast<const float2*>(base + 128);  // row 2*pi+1

    // Gate angle trig (uniform across threads; scalar loads + native trig).
    float gc[6], gs[6];
    #pragma unroll
    for (int k = 0; k < 6; ++k)
        __sincosf(0.5f * tp[k], &gs[k], &gc[k]);

    // Initial product state factors: qubit w = (cos(a_w/2), sin(a_w/2)).
    float A[4][2];
    {
        float ang[4] = {r0.x, r0.y, r1.x, r1.y};
        #pragma unroll
        for (int w = 0; w < 4; ++w)
            __sincosf(0.5f * ang[w], &A[w][1], &A[w][0]);
    }

    // psi real: re[i] = prod of factors; im = 0 (handled by specializing RX0).
    float re[16], im[16];
    {
        float p01[4], p23[4];
        #pragma unroll
        for (int a = 0; a < 4; ++a) {
            p01[a] = A[0][(a >> 1) & 1] * A[1][a & 1];
            p23[a] = A[2][(a >> 1) & 1] * A[3][a & 1];
        }
        #pragma unroll
        for (int i = 0; i < 16; ++i)
            re[i] = p01[i >> 2] * p23[i & 3];
    }

    // Gate 1: RX(t0) on q0 (mask 8), applied to a REAL state:
    //   re' [i] = c*re[i];        im'[i]   = -s*re[i|8]
    //   re'[i|8] = c*re[i|8];     im'[i|8] = -s*re[i]
    {
        float c = gc[0], s = gs[0];
        #pragma unroll
        for (int i = 0; i < 8; ++i) {          // i has bit3 = 0
            int j = i | 8;
            float a = re[i], bb = re[j];
            re[i] = c * a;  im[i] = -s * bb;
            re[j] = c * bb; im[j] = -s * a;
        }
    }

    // RY(t) = [[c,-s],[s,c]] (real coeffs)
    auto apply_ry = [&](int m, float c, float s) {
        #pragma unroll
        for (int i = 0; i < 16; ++i) {
            if (i & m) continue;
            int j = i | m;
            float r0_ = re[i], i0_ = im[i], r1_ = re[j], i1_ = im[j];
            re[i] = c * r0_ - s * r1_;
            im[i] = c * i0_ - s * i1_;
            re[j] = s * r0_ + c * r1_;
            im[j] = s * i0_ + c * i1_;
        }
    };
    // RX(t) = [[c,-is],[-is,c]]
    auto apply_rx = [&](int m, float c, float s) {
        #pragma unroll
        for (int i = 0; i < 16; ++i) {
            if (i & m) continue;
            int j = i | m;
            float r0_ = re[i], i0_ = im[i], r1_ = re[j], i1_ = im[j];
            re[i] =  c * r0_ + s * i1_;
            im[i] =  c * i0_ - s * r1_;
            re[j] =  s * i0_ + c * r1_;
            im[j] = -s * r0_ + c * i1_;
        }
    };
    // RZ(t) = diag(e^{-it/2}, e^{+it/2})
    auto apply_rz = [&](int m, float c, float s) {
        #pragma unroll
        for (int i = 0; i < 16; ++i) {
            float r_ = re[i], i_ = im[i];
            if (i & m) { re[i] = c * r_ - s * i_; im[i] = c * i_ + s * r_; }
            else       { re[i] = c * r_ + s * i_; im[i] = c * i_ - s * r_; }
        }
    };
    // CNOT: swap target pair where control bit set (register rename, free).
    auto apply_cnot = [&](int cm, int tm) {
        #pragma unroll
        for (int i = 0; i < 16; ++i) {
            if ((i & cm) && !(i & tm)) {
                int j = i | tm;
                float tr = re[i]; re[i] = re[j]; re[j] = tr;
                float ti = im[i]; im[i] = im[j]; im[j] = ti;
            }
        }
    };

    apply_ry(4, gc[1], gs[1]);   // RY(t1) q1
    apply_rz(2, gc[2], gs[2]);   // RZ(t2) q2
    apply_cnot(8, 2);            // CNOT(0->2)
    apply_rx(1, gc[3], gs[3]);   // RX(t3) q3
    apply_ry(8, gc[4], gs[4]);   // RY(t4) q0
    apply_cnot(4, 1);            // CNOT(1->3)
    apply_rz(2, gc[5], gs[5]);   // RZ(t5) q2

    // <Z_w> = sum_i p[i] * (-1)^{bit_w(i)}
    float m0 = 0.f, m1 = 0.f, m2 = 0.f, m3 = 0.f;
    #pragma unroll
    for (int i = 0; i < 16; ++i) {
        float p = re[i] * re[i] + im[i] * im[i];
        m0 += (i & 8) ? -p : p;
        m1 += (i & 4) ? -p : p;
        m2 += (i & 2) ? -p : p;
        m3 += (i & 1) ? -p : p;
    }

    *reinterpret_cast<float4*>(out + ((size_t)n << 2)) = make_float4(m0, m1, m2, m3);
}

extern "C" void kernel_launch(void* const* d_in, const int* in_sizes, int n_in,
                              void* d_out, int out_size, void* d_ws, size_t ws_size,
                              hipStream_t stream) {
    const float* x  = (const float*)d_in[0];
    const float* tp = (const float*)d_in[1];
    float* out = (float*)d_out;

    int N = in_sizes[0] / 4;  // number of 2x2 patches = 524288
    const int threads = 256;
    int blocks = (N + threads - 1) / threads;
    qfe_kernel<<<blocks, threads, 0, stream>>>(x, tp, out, N);
}

// Round 3
// 60.361 us; speedup vs baseline: 1.1747x; 1.1127x over previous
//
#include <hip/hip_runtime.h>
#include <math.h>

// Heisenberg-picture closed form. Conjugating each measured Z_w backward
// through the circuit (RX t0 q0 | RY t1 q1 | RZ t2 q2 | CNOT 0->2 | RX t3 q3 |
// RY t4 q0 | CNOT 1->3 | RZ t5 q2) and taking the expectation under the real
// product state (per-qubit <X>=sin a, <Y>=0, <Z>=cos a) gives:
//   m0 = c0*c4*cos(a0) - c2*s4*sin(a0)*sin(a2)
//   m1 = cos(a1 + t1)
//   m2 = c0*cos(a0)*cos(a2)
//   m3 = c3*cos(a1 + t1)*cos(a3)
// with c_k = cos(t_k), s_k = sin(t_k) (FULL gate angles). t5 drops out
// (final RZ commutes with every Z_w). Verified vs special cases:
// all-t=0 keeps the CNOTs -> m2=cos a0 cos a2, m3=cos a1 cos a3;
// t4=pi/2-only hand-checked against the state vector.
//
// Per-thread cost: 4 native sincos/cos on patch angles + ~12 FMA -> the
// kernel is purely memory-bound (8 MB in + 8 MB out).
__global__ __launch_bounds__(256) void qfe_kernel(
    const float* __restrict__ x, const float* __restrict__ tp,
    float* __restrict__ out, int N)
{
    int n = blockIdx.x * blockDim.x + threadIdx.x;
    if (n >= N) return;

    // Wave-uniform gate trig (tp address is uniform -> scalar loads).
    float c0 = __cosf(tp[0]);
    float s1, c1; __sincosf(tp[1], &s1, &c1);
    float c2 = __cosf(tp[2]);
    float c3 = __cosf(tp[3]);
    float s4, c4; __sincosf(tp[4], &s4, &c4);
    float k00 = c0 * c4;     // coeff of cos a0 in m0
    float k01 = c2 * s4;     // coeff of sin a0 sin a2 in m0 (subtracted)

    // n = (b, pi, pj), pj fastest; H=W=128, nh=nw=64.
    int b   = n >> 12;
    int rem = n & 4095;
    int pi  = rem >> 6;
    int pj  = rem & 63;

    const float* base = x + ((size_t)b << 14) + (pi << 8) + (pj << 1);
    float2 r0 = *reinterpret_cast<const float2*>(base);        // a0, a1
    float2 r1 = *reinterpret_cast<const float2*>(base + 128);  // a2, a3

    float sa0, ca0; __sincosf(r0.x, &sa0, &ca0);
    float sa1, ca1; __sincosf(r0.y, &sa1, &ca1);
    float sa2, ca2; __sincosf(r1.x, &sa2, &ca2);
    float ca3 = __cosf(r1.y);

    float u  = c1 * ca1 - s1 * sa1;          // cos(a1 + t1)
    float m0 = k00 * ca0 - k01 * (sa0 * sa2);
    float m1 = u;
    float m2 = c0 * (ca0 * ca2);
    float m3 = c3 * (u * ca3);

    *reinterpret_cast<float4*>(out + ((size_t)n << 2)) = make_float4(m0, m1, m2, m3);
}

extern "C" void kernel_launch(void* const* d_in, const int* in_sizes, int n_in,
                              void* d_out, int out_size, void* d_ws, size_t ws_size,
                              hipStream_t stream) {
    const float* x  = (const float*)d_in[0];
    const float* tp = (const float*)d_in[1];
    float* out = (float*)d_out;

    int N = in_sizes[0] / 4;  // number of 2x2 patches = 524288
    const int threads = 256;
    int blocks = (N + threads - 1) / threads;
    qfe_kernel<<<blocks, threads, 0, stream>>>(x, tp, out, N);
}